// Round 17
// baseline (564.364 us; speedup 1.0000x reference)
//
#include <hip/hip_runtime.h>
#include <hip/hip_bf16.h>

#define HID 128
#define NHEAD 4
#define CAP 96   // per-node slot capacity; Poisson(32) => P(deg>96) ~ 1e-18

typedef __attribute__((ext_vector_type(8))) short bf16x8;
typedef __attribute__((ext_vector_type(4))) float f32x4;
typedef __attribute__((ext_vector_type(2))) float f32x2;

__device__ __forceinline__ unsigned pack2_bf16_rne(float lo, float hi) {
    unsigned a = __float_as_uint(lo);
    a = (a + 0x7fffu + ((a >> 16) & 1u)) >> 16;
    unsigned b = __float_as_uint(hi);
    b = (b + 0x7fffu + ((b >> 16) & 1u)) & 0xffff0000u;
    return a | b;
}

__device__ __forceinline__ unsigned short bf16_rne(float x) {
    unsigned u = __float_as_uint(x);
    u = (u + 0x7fffu + ((u >> 16) & 1u)) >> 16;
    return (unsigned short)u;
}

__device__ __forceinline__ f32x2 unpack_bf(unsigned u) {
    f32x2 r;
    r.x = __uint_as_float(u << 16);
    r.y = __uint_as_float(u & 0xffff0000u);
    return r;
}

__device__ __forceinline__ f32x2 leaky2(f32x2 q) {
    return __builtin_elementwise_max(q, q * 0.2f);
}

__device__ __forceinline__ float row_sum4(float x) {
    x += __int_as_float(__builtin_amdgcn_update_dpp(0, __float_as_int(x), 0xB1, 0xF, 0xF, true));
    x += __int_as_float(__builtin_amdgcn_update_dpp(0, __float_as_int(x), 0x4E, 0xF, 0xF, true));
    return x;
}

// ---------------- CSR build: ballot partition (packed) + weight prep fused ----------------
#define TILE2 1024
__global__ __launch_bounds__(256) void partition_and_prep(
    const int* __restrict__ src, const int* __restrict__ dst,
    int* __restrict__ tails, unsigned* __restrict__ buckets,
    int BCAP, int E, int qg, int ntiles,
    const float* __restrict__ W_src, const float* __restrict__ W_dst,
    const float* __restrict__ W1, const float* __restrict__ W2,
    unsigned short* __restrict__ Wt) {
    if ((int)blockIdx.x >= ntiles) {
        int mat = blockIdx.x - ntiles; // 0..7
        const float* Wf = (mat < 3) ? (W_src + (size_t)mat * 16384)
                        : (mat < 6) ? (W_dst + (size_t)(mat - 3) * 16384)
                        : (mat == 6) ? W1 : W2;
        unsigned short* out = Wt + (size_t)mat * 16384;
        for (int idx = threadIdx.x; idx < 16384; idx += blockDim.x) {
            int k = idx >> 7, nn = idx & 127;
            out[nn * 128 + k] = bf16_rne(Wf[idx]);
        }
        return;
    }
    __shared__ int warr[4][8];
    __shared__ int base_sh[8];
    const int tid = threadIdx.x;
    const int wave = tid >> 6, lane = tid & 63;
    const int e0 = blockIdx.x * TILE2;
    const unsigned long long below = (1ULL << lane) - 1ULL;

    unsigned preg[4];
    int binr[4], rankr[4];
    int wcnt[8] = {0, 0, 0, 0, 0, 0, 0, 0};
#pragma unroll
    for (int j = 0; j < 4; ++j) {
        int idx = e0 + j * 256 + tid;
        bool ok = idx < E;
        int d = ok ? dst[idx] : 0;
        int s = ok ? src[idx] : 0;
        int g = ok ? (d / qg) : -1;
        int dl = d - g * qg;
        preg[j] = (unsigned)s | ((unsigned)dl << 16);
        binr[j] = g;
        int r = 0;
#pragma unroll
        for (int b = 0; b < 8; ++b) {
            unsigned long long mb = __ballot(g == b);
            if (g == b) r = wcnt[b] + (int)__popcll(mb & below);
            wcnt[b] += (int)__popcll(mb);
        }
        rankr[j] = r;
    }
    if (lane == 0) {
#pragma unroll
        for (int b = 0; b < 8; ++b) warr[wave][b] = wcnt[b];
    }
    __syncthreads();
    if (tid < 8) {
        int b = tid, tot = 0;
        int pre[4];
#pragma unroll
        for (int w = 0; w < 4; ++w) { pre[w] = tot; tot += warr[w][b]; }
        base_sh[b] = atomicAdd(&tails[b], tot);
#pragma unroll
        for (int w = 0; w < 4; ++w) warr[w][b] = pre[w];
    }
    __syncthreads();
#pragma unroll
    for (int j = 0; j < 4; ++j) {
        int g = binr[j];
        if (g >= 0) {
            int pos = base_sh[g] + warr[wave][g] + rankr[j];
            if (pos < BCAP) buckets[(size_t)g * BCAP + pos] = preg[j];
        }
    }
}

// group g scans ITS bucket only; cnt atomics + slots writes XCD-local.
__global__ __launch_bounds__(256) void fill_slots(
    const unsigned* __restrict__ buckets, const int* __restrict__ tails,
    int* __restrict__ cnt, int* __restrict__ slots, int BCAP, int qg) {
    int g = blockIdx.x & 7;
    int blk = blockIdx.x >> 3;
    int nblk = gridDim.x >> 3;
    int c = tails[g]; if (c > BCAP) c = BCAP;
    int dbase = g * qg;
    const unsigned* b = buckets + (size_t)g * BCAP;
    for (int i = blk * 256 + threadIdx.x; i < c; i += nblk * 256) {
        unsigned p = b[i];
        int d = dbase + (int)(p >> 16);
        int pos = atomicAdd(&cnt[d], 1);
        if (pos < CAP) slots[(size_t)d * CAP + pos] = (int)(p & 0xFFFFu);
    }
}

// ---------------- vector GEMM (K=32 input projection, bf16 out) ----------------
#define GR 64
__global__ __launch_bounds__(256) void gemm_in(const float* __restrict__ A,
                                               const float* __restrict__ W,
                                               const float* __restrict__ bias,
                                               unsigned short* __restrict__ C16, int n) {
    const int K = 32;
    __shared__ __align__(16) float a_sh[GR * K];
    const int tid = threadIdx.x;
    const int tx = tid & 31;
    const int ty = tid >> 5;
    const int r0 = blockIdx.x * GR;

    for (int i = tid * 4; i < GR * K; i += 1024) {
        int r = i / K, k = i % K;
        int gr = r0 + r;
        float4 v = make_float4(0.f, 0.f, 0.f, 0.f);
        if (gr < n) v = *(const float4*)&A[(size_t)gr * K + k];
        *(float4*)&a_sh[i] = v;
    }
    __syncthreads();

    float4 acc[8];
#pragma unroll
    for (int r = 0; r < 8; ++r) acc[r] = make_float4(0.f, 0.f, 0.f, 0.f);

    const float* ab = &a_sh[ty * 8 * K];
    const float* wb = &W[tx * 4];

    for (int k = 0; k < K; k += 4) {
        float4 w0 = *(const float4*)&wb[(size_t)(k + 0) * 128];
        float4 w1 = *(const float4*)&wb[(size_t)(k + 1) * 128];
        float4 w2 = *(const float4*)&wb[(size_t)(k + 2) * 128];
        float4 w3 = *(const float4*)&wb[(size_t)(k + 3) * 128];
#pragma unroll
        for (int r = 0; r < 8; ++r) {
            float4 a4 = *(const float4*)&ab[r * K + k];
            acc[r].x = fmaf(a4.x, w0.x, acc[r].x);
            acc[r].y = fmaf(a4.x, w0.y, acc[r].y);
            acc[r].z = fmaf(a4.x, w0.z, acc[r].z);
            acc[r].w = fmaf(a4.x, w0.w, acc[r].w);
            acc[r].x = fmaf(a4.y, w1.x, acc[r].x);
            acc[r].y = fmaf(a4.y, w1.y, acc[r].y);
            acc[r].z = fmaf(a4.y, w1.z, acc[r].z);
            acc[r].w = fmaf(a4.y, w1.w, acc[r].w);
            acc[r].x = fmaf(a4.z, w2.x, acc[r].x);
            acc[r].y = fmaf(a4.z, w2.y, acc[r].y);
            acc[r].z = fmaf(a4.z, w2.z, acc[r].z);
            acc[r].w = fmaf(a4.z, w2.w, acc[r].w);
            acc[r].x = fmaf(a4.w, w3.x, acc[r].x);
            acc[r].y = fmaf(a4.w, w3.y, acc[r].y);
            acc[r].z = fmaf(a4.w, w3.z, acc[r].z);
            acc[r].w = fmaf(a4.w, w3.w, acc[r].w);
        }
    }

    float4 b4 = *(const float4*)&bias[tx * 4];
#pragma unroll
    for (int r = 0; r < 8; ++r) {
        int gr = r0 + ty * 8 + r;
        if (gr < n) {
            uint2 st;
            st.x = pack2_bf16_rne(acc[r].x + b4.x, acc[r].y + b4.y);
            st.y = pack2_bf16_rne(acc[r].z + b4.z, acc[r].w + b4.w);
            *(uint2*)&C16[(size_t)gr * 128 + tx * 4] = st;
        }
    }
}

// ---------------- MFMA GEMM (single output, swapped operands, packed stores) ----------------
template <bool RELU, bool F32OUT, bool BF16OUT>
__global__ __launch_bounds__(256) void gemm_mfma(
    const unsigned short* __restrict__ A16,
    const unsigned short* __restrict__ Bt16,
    const float* __restrict__ bias,
    float* __restrict__ Cf, unsigned short* __restrict__ C16, int n) {
    const int wave = threadIdx.x >> 6;
    const int lane = threadIdx.x & 63;
    const int r = lane & 15, g = lane >> 4;
    const int m0 = blockIdx.x * 64 + wave * 16;
    int ra = m0 + r; if (ra > n - 1) ra = n - 1;
    const bf16x8* Arow = (const bf16x8*)(A16 + (size_t)ra * 128);
    bf16x8 a0 = Arow[g];
    bf16x8 a1 = Arow[4 + g];
    bf16x8 a2 = Arow[8 + g];
    bf16x8 a3 = Arow[12 + g];
    const int row = m0 + r;
    const bool rok = row < n;
#pragma unroll
    for (int ct = 0; ct < 8; ++ct) {
        const bf16x8* Brow = (const bf16x8*)(Bt16 + (size_t)(ct * 16 + r) * 128);
        f32x4 acc = {0.f, 0.f, 0.f, 0.f};
        acc = __builtin_amdgcn_mfma_f32_16x16x32_bf16(Brow[g], a0, acc, 0, 0, 0);
        acc = __builtin_amdgcn_mfma_f32_16x16x32_bf16(Brow[4 + g], a1, acc, 0, 0, 0);
        acc = __builtin_amdgcn_mfma_f32_16x16x32_bf16(Brow[8 + g], a2, acc, 0, 0, 0);
        acc = __builtin_amdgcn_mfma_f32_16x16x32_bf16(Brow[12 + g], a3, acc, 0, 0, 0);
        const int col = ct * 16 + g * 4;
        float4 b4 = *(const float4*)&bias[col];
        float o0 = acc[0] + b4.x, o1 = acc[1] + b4.y;
        float o2 = acc[2] + b4.z, o3 = acc[3] + b4.w;
        if (RELU) {
            o0 = fmaxf(o0, 0.f); o1 = fmaxf(o1, 0.f);
            o2 = fmaxf(o2, 0.f); o3 = fmaxf(o3, 0.f);
        }
        if (rok) {
            if (F32OUT)
                *(float4*)&Cf[(size_t)row * 128 + col] = make_float4(o0, o1, o2, o3);
            if (BF16OUT) {
                uint2 st;
                st.x = pack2_bf16_rne(o0, o1);
                st.y = pack2_bf16_rne(o2, o3);
                *(uint2*)&C16[(size_t)row * 128 + col] = st;
            }
        }
    }
}

// ---------------- MFMA GEMM dual (swapped operands, packed bf16 stores) ----------------
__global__ __launch_bounds__(256) void gemm_mfma_dual(
    const unsigned short* __restrict__ A16,
    const unsigned short* __restrict__ B1t, const unsigned short* __restrict__ B2t,
    const float* __restrict__ bias1, const float* __restrict__ bias2,
    unsigned short* __restrict__ C1, unsigned short* __restrict__ C2, int n) {
    const int wave = threadIdx.x >> 6;
    const int lane = threadIdx.x & 63;
    const int r = lane & 15, g = lane >> 4;
    const int m0 = blockIdx.x * 64 + wave * 16;
    int ra = m0 + r; if (ra > n - 1) ra = n - 1;
    const bf16x8* Arow = (const bf16x8*)(A16 + (size_t)ra * 128);
    bf16x8 a0 = Arow[g];
    bf16x8 a1 = Arow[4 + g];
    bf16x8 a2 = Arow[8 + g];
    bf16x8 a3 = Arow[12 + g];
    const int row = m0 + r;
    const bool rok = row < n;
#pragma unroll
    for (int ct = 0; ct < 8; ++ct) {
        const int col = ct * 16 + g * 4;
        {
            const bf16x8* Brow = (const bf16x8*)(B1t + (size_t)(ct * 16 + r) * 128);
            f32x4 acc = {0.f, 0.f, 0.f, 0.f};
            acc = __builtin_amdgcn_mfma_f32_16x16x32_bf16(Brow[g], a0, acc, 0, 0, 0);
            acc = __builtin_amdgcn_mfma_f32_16x16x32_bf16(Brow[4 + g], a1, acc, 0, 0, 0);
            acc = __builtin_amdgcn_mfma_f32_16x16x32_bf16(Brow[8 + g], a2, acc, 0, 0, 0);
            acc = __builtin_amdgcn_mfma_f32_16x16x32_bf16(Brow[12 + g], a3, acc, 0, 0, 0);
            float4 b4 = *(const float4*)&bias1[col];
            if (rok) {
                uint2 st;
                st.x = pack2_bf16_rne(acc[0] + b4.x, acc[1] + b4.y);
                st.y = pack2_bf16_rne(acc[2] + b4.z, acc[3] + b4.w);
                *(uint2*)&C1[(size_t)row * 128 + col] = st;
            }
        }
        {
            const bf16x8* Brow = (const bf16x8*)(B2t + (size_t)(ct * 16 + r) * 128);
            f32x4 acc = {0.f, 0.f, 0.f, 0.f};
            acc = __builtin_amdgcn_mfma_f32_16x16x32_bf16(Brow[g], a0, acc, 0, 0, 0);
            acc = __builtin_amdgcn_mfma_f32_16x16x32_bf16(Brow[4 + g], a1, acc, 0, 0, 0);
            acc = __builtin_amdgcn_mfma_f32_16x16x32_bf16(Brow[8 + g], a2, acc, 0, 0, 0);
            acc = __builtin_amdgcn_mfma_f32_16x16x32_bf16(Brow[12 + g], a3, acc, 0, 0, 0);
            float4 b4 = *(const float4*)&bias2[col];
            if (rok) {
                uint2 st;
                st.x = pack2_bf16_rne(acc[0] + b4.x, acc[1] + b4.y);
                st.y = pack2_bf16_rne(acc[2] + b4.z, acc[3] + b4.w);
                *(uint2*)&C2[(size_t)row * 128 + col] = st;
            }
        }
    }
}

// ---------------- fused GATv2 aggregate + residuals + LayerNorm + ReLU ----------------
template <bool LAST>
__global__ __launch_bounds__(256) void gat_aggregate(
    unsigned short* __restrict__ h16,        // [n,128] bf16 residual in / out
    const unsigned short* __restrict__ hs16, // [n,128] bf16 (gathered)
    const unsigned short* __restrict__ hd16, // [n,128] bf16 (scores only)
    const int* __restrict__ cnt,             // [n] in-degree
    const int* __restrict__ slots,           // [n*CAP] src ids
    const float* __restrict__ attn,
    const float* __restrict__ ln_g, const float* __restrict__ ln_b,
    float* __restrict__ out_f32, int n) {
    int v = (blockIdx.x * blockDim.x + threadIdx.x) >> 6;
    int lane = threadIdx.x & 63;
    if (v >= n) return;
    const int lh = lane & 15;
    const int quarter = lane >> 4;
    const int f0 = lh * 8;
    const unsigned fb = (unsigned)lh << 4;

    const float L2E = 1.4426950408889634f;
    f32x2 av0, av1, av2, av3;
    {
        float4 aa = *(const float4*)&attn[f0];
        float4 ab = *(const float4*)&attn[f0 + 4];
        av0 = (f32x2){aa.x, aa.y} * L2E; av1 = (f32x2){aa.z, aa.w} * L2E;
        av2 = (f32x2){ab.x, ab.y} * L2E; av3 = (f32x2){ab.z, ab.w} * L2E;
    }
    const char* hsb = (const char*)hs16;
    f32x2 hd0, hd1, hd2, hd3;
    {
        uint4 wd = *(const uint4*)((const char*)hd16 + ((size_t)(unsigned)v << 8) + fb);
        hd0 = unpack_bf(wd.x); hd1 = unpack_bf(wd.y);
        hd2 = unpack_bf(wd.z); hd3 = unpack_bf(wd.w);
    }
    uint4 wv = *(const uint4*)(hsb + ((size_t)(unsigned)v << 8) + fb);
    f32x2 sv0 = unpack_bf(wv.x), sv1 = unpack_bf(wv.y);
    f32x2 sv2 = unpack_bf(wv.z), sv3 = unpack_bf(wv.w);
    float m;
    {
        f32x2 q0 = leaky2(sv0 + hd0), q1 = leaky2(sv1 + hd1);
        f32x2 q2 = leaky2(sv2 + hd2), q3 = leaky2(sv3 + hd3);
        f32x2 dt = q0 * av0; dt += q1 * av1; dt += q2 * av2; dt += q3 * av3;
        m = row_sum4(dt.x + dt.y);
    }
    const bool q0lane = (quarter == 0);
    float s = q0lane ? 1.f : 0.f;
    f32x2 acc0 = q0lane ? sv0 : (f32x2){0.f, 0.f};
    f32x2 acc1 = q0lane ? sv1 : (f32x2){0.f, 0.f};
    f32x2 acc2 = q0lane ? sv2 : (f32x2){0.f, 0.f};
    f32x2 acc3 = q0lane ? sv3 : (f32x2){0.f, 0.f};

    int deg = cnt[v]; if (deg > CAP) deg = CAP;
    const int* srow = slots + (size_t)v * CAP;
    int end4 = deg & ~3;

    auto process = [&](uint4 w) {
        f32x2 g0 = unpack_bf(w.x), g1 = unpack_bf(w.y);
        f32x2 g2 = unpack_bf(w.z), g3 = unpack_bf(w.w);
        f32x2 p0 = leaky2(g0 + hd0), p1 = leaky2(g1 + hd1);
        f32x2 p2 = leaky2(g2 + hd2), p3 = leaky2(g3 + hd3);
        f32x2 dt = p0 * av0; dt += p1 * av1; dt += p2 * av2; dt += p3 * av3;
        float sc = row_sum4(dt.x + dt.y);
        float d0 = sc - m;
        if (__builtin_expect(__any(d0 > 8.f), 0)) {
            float dmx = fmaxf(d0, __shfl_xor(d0, 16));
            dmx = fmaxf(dmx, __shfl_xor(dmx, 32));
            float mn = m + fmaxf(dmx, 0.f);
            float rr = exp2f(m - mn);
            s *= rr; acc0 *= rr; acc1 *= rr; acc2 *= rr; acc3 *= rr;
            m = mn; d0 = sc - m;
        }
        float e = exp2f(d0);
        s += e;
        acc0 += g0 * e; acc1 += g1 * e; acc2 += g2 * e; acc3 += g3 * e;
    };

    if (end4 > 0) {
        uint4 w = *(const uint4*)(hsb + ((size_t)(unsigned)srow[quarter] << 8) + fb);
        int un = (4 < end4) ? srow[4 + quarter] : 0;
        for (int i = 4; i < end4; i += 4) {
            uint4 wn = *(const uint4*)(hsb + ((size_t)(unsigned)un << 8) + fb);
            if (i + 4 < end4) un = srow[i + 4 + quarter];
            process(w);
            w = wn;
        }
        process(w);
    }
    if (end4 < deg) {
        int idx = end4 + quarter;
        bool act = idx < deg;
        int u = srow[act ? idx : end4];
        uint4 w = *(const uint4*)(hsb + ((size_t)(unsigned)u << 8) + fb);
        f32x2 g0 = unpack_bf(w.x), g1 = unpack_bf(w.y);
        f32x2 g2 = unpack_bf(w.z), g3 = unpack_bf(w.w);
        f32x2 p0 = leaky2(g0 + hd0), p1 = leaky2(g1 + hd1);
        f32x2 p2 = leaky2(g2 + hd2), p3 = leaky2(g3 + hd3);
        f32x2 dt = p0 * av0; dt += p1 * av1; dt += p2 * av2; dt += p3 * av3;
        float sc = row_sum4(dt.x + dt.y);
        float d0 = sc - m;
        float d0m = act ? d0 : -1e30f;
        if (__builtin_expect(__any(d0m > 8.f), 0)) {
            float dmx = fmaxf(d0m, __shfl_xor(d0m, 16));
            dmx = fmaxf(dmx, __shfl_xor(dmx, 32));
            float mn = m + fmaxf(dmx, 0.f);
            float rr = exp2f(m - mn);
            s *= rr; acc0 *= rr; acc1 *= rr; acc2 *= rr; acc3 *= rr;
            m = mn; d0 = sc - m;
        }
        float e = act ? exp2f(d0) : 0.f;
        s += e;
        acc0 += g0 * e; acc1 += g1 * e; acc2 += g2 * e; acc3 += g3 * e;
    }
#pragma unroll
    for (int d = 16; d <= 32; d <<= 1) {
        s += __shfl_xor(s, d);
        acc0.x += __shfl_xor(acc0.x, d); acc0.y += __shfl_xor(acc0.y, d);
        acc1.x += __shfl_xor(acc1.x, d); acc1.y += __shfl_xor(acc1.y, d);
        acc2.x += __shfl_xor(acc2.x, d); acc2.y += __shfl_xor(acc2.y, d);
        acc3.x += __shfl_xor(acc3.x, d); acc3.y += __shfl_xor(acc3.y, d);
    }
    float inv = 1.0f / (s + 1e-9f);

    f32x2 hv0, hv1, hv2, hv3;
    {
        uint4 wh = *(const uint4*)((const char*)h16 + ((size_t)(unsigned)v << 8) + fb);
        hv0 = unpack_bf(wh.x); hv1 = unpack_bf(wh.y);
        hv2 = unpack_bf(wh.z); hv3 = unpack_bf(wh.w);
    }
    f32x2 x0 = acc0 * inv + hv0 * 2.f;
    f32x2 x1 = acc1 * inv + hv1 * 2.f;
    f32x2 x2 = acc2 * inv + hv2 * 2.f;
    f32x2 x3 = acc3 * inv + hv3 * 2.f;

    f32x2 sum2 = (x0 + x1) + (x2 + x3);
    f32x2 sq2 = x0 * x0 + x1 * x1 + x2 * x2 + x3 * x3;
    float sum = sum2.x + sum2.y, sq = sq2.x + sq2.y;
#pragma unroll
    for (int d = 1; d < 64; d <<= 1) { sum += __shfl_xor(sum, d); sq += __shfl_xor(sq, d); }
    float mu = sum * (1.f / 512.f);
    float var = sq * (1.f / 512.f) - mu * mu;
    float rstd = rsqrtf(var + 1e-5f);
    f32x2 g0v, g1v, g2v, g3v, b0v, b1v, b2v, b3v;
    {
        float4 ga = *(const float4*)&ln_g[f0];
        float4 gb = *(const float4*)&ln_g[f0 + 4];
        float4 ba = *(const float4*)&ln_b[f0];
        float4 bb = *(const float4*)&ln_b[f0 + 4];
        g0v = (f32x2){ga.x, ga.y}; g1v = (f32x2){ga.z, ga.w};
        g2v = (f32x2){gb.x, gb.y}; g3v = (f32x2){gb.z, gb.w};
        b0v = (f32x2){ba.x, ba.y}; b1v = (f32x2){ba.z, ba.w};
        b2v = (f32x2){bb.x, bb.y}; b3v = (f32x2){bb.z, bb.w};
    }
    f32x2 zero = {0.f, 0.f};
    f32x2 y0 = __builtin_elementwise_max((x0 - mu) * rstd * g0v + b0v, zero);
    f32x2 y1 = __builtin_elementwise_max((x1 - mu) * rstd * g1v + b1v, zero);
    f32x2 y2 = __builtin_elementwise_max((x2 - mu) * rstd * g2v + b2v, zero);
    f32x2 y3 = __builtin_elementwise_max((x3 - mu) * rstd * g3v + b3v, zero);
    if (quarter == 0) {
        uint4 st;
        st.x = pack2_bf16_rne(y0.x, y0.y);
        st.y = pack2_bf16_rne(y1.x, y1.y);
        st.z = pack2_bf16_rne(y2.x, y2.y);
        st.w = pack2_bf16_rne(y3.x, y3.y);
        *(uint4*)((char*)h16 + ((size_t)v << 8) + fb) = st;
        if (LAST) {
            float* orow = &out_f32[(size_t)v * 128 + f0];
            *(float4*)orow = make_float4(y0.x, y0.y, y1.x, y1.y);
            *(float4*)(orow + 4) = make_float4(y2.x, y2.y, y3.x, y3.y);
        }
    }
}

// ---------------- epilogue ----------------
__global__ __launch_bounds__(256) void mean_partial(const float4* __restrict__ src,
                                                    float* __restrict__ gacc, size_t n4) {
    int tid = threadIdx.x;
    size_t i = blockIdx.x * (size_t)256 + tid;
    size_t stride = (size_t)gridDim.x * 256;
    float ax = 0.f, ay = 0.f, az = 0.f, aw = 0.f;
    for (; i < n4; i += stride) {
        float4 v = src[i];
        ax += v.x; ay += v.y; az += v.z; aw += v.w;
    }
    __shared__ float4 sb[256];
    sb[tid] = make_float4(ax, ay, az, aw);
    __syncthreads();
    for (int off = 128; off >= 32; off >>= 1) {
        if (tid < off) {
            float4 o = sb[tid + off];
            sb[tid].x += o.x; sb[tid].y += o.y; sb[tid].z += o.z; sb[tid].w += o.w;
        }
        __syncthreads();
    }
    if (tid < 32) {
        float4 a = sb[tid];
        atomicAdd(&gacc[tid * 4 + 0], a.x);
        atomicAdd(&gacc[tid * 4 + 1], a.y);
        atomicAdd(&gacc[tid * 4 + 2], a.z);
        atomicAdd(&gacc[tid * 4 + 3], a.w);
    }
}

__global__ void graph_mean_final(const float* __restrict__ gacc, float* __restrict__ out, int n) {
    int c = threadIdx.x; // 128
    out[c] = gacc[c] / (float)n;
}

__global__ __launch_bounds__(256) void heads_kernel(
    const float* __restrict__ z,
    const float* __restrict__ Wa, const float* __restrict__ ba,
    const float* __restrict__ Wg, const float* __restrict__ bg,
    const float* __restrict__ Wal, const float* __restrict__ bal,
    const float* __restrict__ Wn, const float* __restrict__ bn,
    const float* __restrict__ Wt, const float* __restrict__ bt,
    float* __restrict__ logits, float* __restrict__ spawn, int n) {
    int v = (blockIdx.x * blockDim.x + threadIdx.x) >> 6;
    int lane = threadIdx.x & 63;
    if (v >= n) return;
    int f0 = lane * 2;
    float2 zv = *(const float2*)&z[(size_t)v * 128 + f0];
    float p0 = zv.x * Wa[f0 * 2]     + zv.y * Wa[(f0 + 1) * 2];
    float p1 = zv.x * Wa[f0 * 2 + 1] + zv.y * Wa[(f0 + 1) * 2 + 1];
    float p2 = zv.x * Wg[f0]  + zv.y * Wg[f0 + 1];
    float p3 = zv.x * Wal[f0] + zv.y * Wal[f0 + 1];
    float p4 = zv.x * Wn[f0]  + zv.y * Wn[f0 + 1];
    float p5 = zv.x * Wt[f0]  + zv.y * Wt[f0 + 1];
#pragma unroll
    for (int d = 1; d < 64; d <<= 1) {
        p0 += __shfl_xor(p0, d); p1 += __shfl_xor(p1, d); p2 += __shfl_xor(p2, d);
        p3 += __shfl_xor(p3, d); p4 += __shfl_xor(p4, d); p5 += __shfl_xor(p5, d);
    }
    if (lane == 0) {
        logits[(size_t)v * 2 + 0] = p0 + ba[0];
        logits[(size_t)v * 2 + 1] = p1 + ba[1];
        float gamma = 5.f / (1.f + __expf(-(p2 + bg[0])));
        float alpha = 2.f / (1.f + __expf(-(p3 + bal[0])));
        float noise = 1.f / (1.f + __expf(-(p4 + bn[0])));
        float theta = tanhf(p5 + bt[0]) * 3.14159265358979323846f;
        spawn[(size_t)v * 4 + 0] = gamma;
        spawn[(size_t)v * 4 + 1] = alpha;
        spawn[(size_t)v * 4 + 2] = noise;
        spawn[(size_t)v * 4 + 3] = theta;
    }
}

extern "C" void kernel_launch(void* const* d_in, const int* in_sizes, int n_in,
                              void* d_out, int out_size, void* d_ws, size_t ws_size,
                              hipStream_t stream) {
    const float* node_feats = (const float*)d_in[0];
    const int*   src  = (const int*)d_in[1];
    const int*   dst  = (const int*)d_in[2];
    const float* W_in = (const float*)d_in[3];
    const float* b_in = (const float*)d_in[4];
    const float* W_src = (const float*)d_in[5];
    const float* b_src = (const float*)d_in[6];
    const float* W_dst = (const float*)d_in[7];
    const float* b_dst = (const float*)d_in[8];
    const float* attn  = (const float*)d_in[9];
    const float* ln_g  = (const float*)d_in[10];
    const float* ln_b  = (const float*)d_in[11];
    const float* W1 = (const float*)d_in[12]; const float* b1 = (const float*)d_in[13];
    const float* W2 = (const float*)d_in[14]; const float* b2 = (const float*)d_in[15];
    const float* Wa = (const float*)d_in[16]; const float* ba = (const float*)d_in[17];
    const float* Wg = (const float*)d_in[18]; const float* bg = (const float*)d_in[19];
    const float* Wal = (const float*)d_in[20]; const float* bal = (const float*)d_in[21];
    const float* Wn = (const float*)d_in[22]; const float* bn = (const float*)d_in[23];
    const float* Wt = (const float*)d_in[24]; const float* bt = (const float*)d_in[25];

    const int n = in_sizes[0] / 32;  // 50000
    const int E = in_sizes[1];       // 1600000
    const int qg = (n + 7) / 8;      // 6250 < 8192 (13-bit local dst)
    const int BCAP = 240 * 1024;
    const int ntiles = (E + TILE2 - 1) / TILE2;

    char* ws = (char*)d_ws;
    size_t off = 0;
    auto alloc = [&](size_t bytes) -> void* {
        void* p = ws + off;
        off = (off + bytes + 255) & ~(size_t)255;
        return p;
    };
    float* Bz  = (float*)alloc((size_t)n * 128 * 4);
    unsigned short* h16  = (unsigned short*)alloc((size_t)n * 128 * 2);
    unsigned short* hs16 = (unsigned short*)alloc((size_t)n * 128 * 2);
    unsigned short* hd16 = (unsigned short*)alloc((size_t)n * 128 * 2);
    unsigned short* Wt16 = (unsigned short*)alloc((size_t)8 * 16384 * 2);
    int* cnt   = (int*)alloc((size_t)n * 4);
    int* slots = (int*)alloc((size_t)n * CAP * 4);
    unsigned* buckets = (unsigned*)alloc((size_t)8 * BCAP * 4);
    int* tails = (int*)alloc(8 * 4);
    float* gacc = (float*)alloc(128 * 4);

    float* out = (float*)d_out;
    float* out_gemb   = out;
    float* out_nemb   = out + 128;
    float* out_logits = out + 128 + (size_t)n * 128;
    float* out_spawn  = out_logits + (size_t)n * 2;

    hipMemsetAsync(cnt, 0, (size_t)n * 4, stream);
    hipMemsetAsync(tails, 0, 8 * 4, stream);
    hipMemsetAsync(gacc, 0, 128 * 4, stream);

    partition_and_prep<<<ntiles + 8, 256, 0, stream>>>(
        src, dst, tails, buckets, BCAP, E, qg, ntiles, W_src, W_dst, W1, W2, Wt16);
    fill_slots<<<2048, 256, 0, stream>>>(buckets, tails, cnt, slots, BCAP, qg);

    int gemm_grid = (n + GR - 1) / GR;
    int mfma_grid = (n + 63) / 64;

    gemm_in<<<gemm_grid, 256, 0, stream>>>(node_feats, W_in, b_in, h16, n);

    for (int l = 0; l < 3; ++l) {
        gemm_mfma_dual<<<mfma_grid, 256, 0, stream>>>(
            h16, Wt16 + (size_t)l * 16384, Wt16 + (size_t)(3 + l) * 16384,
            b_src + l * 128, b_dst + l * 128, hs16, hd16, n);
        if (l == 2)
            gat_aggregate<true><<<(n + 3) / 4, 256, 0, stream>>>(
                h16, hs16, hd16, cnt, slots, attn + l * 128, ln_g + l * 128,
                ln_b + l * 128, out_nemb, n);
        else
            gat_aggregate<false><<<(n + 3) / 4, 256, 0, stream>>>(
                h16, hs16, hd16, cnt, slots, attn + l * 128, ln_g + l * 128,
                ln_b + l * 128, nullptr, n);
    }

    gemm_mfma<true, false, true><<<mfma_grid, 256, 0, stream>>>(
        h16, Wt16 + (size_t)6 * 16384, b1, nullptr, hs16, n);           // z1 (bf16)
    gemm_mfma<true, true, false><<<mfma_grid, 256, 0, stream>>>(
        hs16, Wt16 + (size_t)7 * 16384, b2, Bz, nullptr, n);            // z (f32)

    mean_partial<<<512, 256, 0, stream>>>((const float4*)out_nemb, gacc, (size_t)n * 32);
    graph_mean_final<<<1, 128, 0, stream>>>(gacc, out_gemb, n);
    heads_kernel<<<(n + 3) / 4, 256, 0, stream>>>(Bz, Wa, ba, Wg, bg, Wal, bal,
                                                  Wn, bn, Wt, bt, out_logits, out_spawn, n);
}

// Round 18
// 519.585 us; speedup vs baseline: 1.0862x; 1.0862x over previous
//
#include <hip/hip_runtime.h>
#include <hip/hip_bf16.h>

#define HID 128
#define NHEAD 4
#define CAP 96   // per-node slot capacity; Poisson(32) => P(deg>96) ~ 1e-18

typedef __attribute__((ext_vector_type(8))) short bf16x8;
typedef __attribute__((ext_vector_type(4))) float f32x4;
typedef __attribute__((ext_vector_type(2))) float f32x2;

__device__ __forceinline__ unsigned pack2_bf16_rne(float lo, float hi) {
    unsigned a = __float_as_uint(lo);
    a = (a + 0x7fffu + ((a >> 16) & 1u)) >> 16;
    unsigned b = __float_as_uint(hi);
    b = (b + 0x7fffu + ((b >> 16) & 1u)) & 0xffff0000u;
    return a | b;
}

__device__ __forceinline__ unsigned short bf16_rne(float x) {
    unsigned u = __float_as_uint(x);
    u = (u + 0x7fffu + ((u >> 16) & 1u)) >> 16;
    return (unsigned short)u;
}

__device__ __forceinline__ f32x2 unpack_bf(unsigned u) {
    f32x2 r;
    r.x = __uint_as_float(u << 16);
    r.y = __uint_as_float(u & 0xffff0000u);
    return r;
}

__device__ __forceinline__ f32x2 leaky2(f32x2 q) {
    return __builtin_elementwise_max(q, q * 0.2f);
}

__device__ __forceinline__ float row_sum4(float x) {
    x += __int_as_float(__builtin_amdgcn_update_dpp(0, __float_as_int(x), 0xB1, 0xF, 0xF, true));
    x += __int_as_float(__builtin_amdgcn_update_dpp(0, __float_as_int(x), 0x4E, 0xF, 0xF, true));
    return x;
}

// ---------------- CSR build: ballot partition (packed) + weight prep fused ----------------
#define TILE2 1024
__global__ __launch_bounds__(256) void partition_and_prep(
    const int* __restrict__ src, const int* __restrict__ dst,
    int* __restrict__ tails, unsigned* __restrict__ buckets,
    int BCAP, int E, int qg, int ntiles,
    const float* __restrict__ W_src, const float* __restrict__ W_dst,
    const float* __restrict__ W1, const float* __restrict__ W2,
    unsigned short* __restrict__ Wt) {
    if ((int)blockIdx.x >= ntiles) {
        int mat = blockIdx.x - ntiles; // 0..7
        const float* Wf = (mat < 3) ? (W_src + (size_t)mat * 16384)
                        : (mat < 6) ? (W_dst + (size_t)(mat - 3) * 16384)
                        : (mat == 6) ? W1 : W2;
        unsigned short* out = Wt + (size_t)mat * 16384;
        for (int idx = threadIdx.x; idx < 16384; idx += blockDim.x) {
            int k = idx >> 7, nn = idx & 127;
            out[nn * 128 + k] = bf16_rne(Wf[idx]);
        }
        return;
    }
    __shared__ int warr[4][8];
    __shared__ int base_sh[8];
    const int tid = threadIdx.x;
    const int wave = tid >> 6, lane = tid & 63;
    const int e0 = blockIdx.x * TILE2;
    const unsigned long long below = (1ULL << lane) - 1ULL;

    unsigned preg[4];
    int binr[4], rankr[4];
    int wcnt[8] = {0, 0, 0, 0, 0, 0, 0, 0};
#pragma unroll
    for (int j = 0; j < 4; ++j) {
        int idx = e0 + j * 256 + tid;
        bool ok = idx < E;
        int d = ok ? dst[idx] : 0;
        int s = ok ? src[idx] : 0;
        int g = ok ? (d / qg) : -1;
        int dl = d - g * qg;
        preg[j] = (unsigned)s | ((unsigned)dl << 16);
        binr[j] = g;
        int r = 0;
#pragma unroll
        for (int b = 0; b < 8; ++b) {
            unsigned long long mb = __ballot(g == b);
            if (g == b) r = wcnt[b] + (int)__popcll(mb & below);
            wcnt[b] += (int)__popcll(mb);
        }
        rankr[j] = r;
    }
    if (lane == 0) {
#pragma unroll
        for (int b = 0; b < 8; ++b) warr[wave][b] = wcnt[b];
    }
    __syncthreads();
    if (tid < 8) {
        int b = tid, tot = 0;
        int pre[4];
#pragma unroll
        for (int w = 0; w < 4; ++w) { pre[w] = tot; tot += warr[w][b]; }
        base_sh[b] = atomicAdd(&tails[b], tot);
#pragma unroll
        for (int w = 0; w < 4; ++w) warr[w][b] = pre[w];
    }
    __syncthreads();
#pragma unroll
    for (int j = 0; j < 4; ++j) {
        int g = binr[j];
        if (g >= 0) {
            int pos = base_sh[g] + warr[wave][g] + rankr[j];
            if (pos < BCAP) buckets[(size_t)g * BCAP + pos] = preg[j];
        }
    }
}

// group g scans ITS bucket only; cnt atomics + slots writes XCD-local.
__global__ __launch_bounds__(256) void fill_slots(
    const unsigned* __restrict__ buckets, const int* __restrict__ tails,
    int* __restrict__ cnt, int* __restrict__ slots, int BCAP, int qg) {
    int g = blockIdx.x & 7;
    int blk = blockIdx.x >> 3;
    int nblk = gridDim.x >> 3;
    int c = tails[g]; if (c > BCAP) c = BCAP;
    int dbase = g * qg;
    const unsigned* b = buckets + (size_t)g * BCAP;
    for (int i = blk * 256 + threadIdx.x; i < c; i += nblk * 256) {
        unsigned p = b[i];
        int d = dbase + (int)(p >> 16);
        int pos = atomicAdd(&cnt[d], 1);
        if (pos < CAP) slots[(size_t)d * CAP + pos] = (int)(p & 0xFFFFu);
    }
}

// ---------------- vector GEMM (K=32 input projection, bf16 out) ----------------
#define GR 64
__global__ __launch_bounds__(256) void gemm_in(const float* __restrict__ A,
                                               const float* __restrict__ W,
                                               const float* __restrict__ bias,
                                               unsigned short* __restrict__ C16, int n) {
    const int K = 32;
    __shared__ __align__(16) float a_sh[GR * K];
    const int tid = threadIdx.x;
    const int tx = tid & 31;
    const int ty = tid >> 5;
    const int r0 = blockIdx.x * GR;

    for (int i = tid * 4; i < GR * K; i += 1024) {
        int r = i / K, k = i % K;
        int gr = r0 + r;
        float4 v = make_float4(0.f, 0.f, 0.f, 0.f);
        if (gr < n) v = *(const float4*)&A[(size_t)gr * K + k];
        *(float4*)&a_sh[i] = v;
    }
    __syncthreads();

    float4 acc[8];
#pragma unroll
    for (int r = 0; r < 8; ++r) acc[r] = make_float4(0.f, 0.f, 0.f, 0.f);

    const float* ab = &a_sh[ty * 8 * K];
    const float* wb = &W[tx * 4];

    for (int k = 0; k < K; k += 4) {
        float4 w0 = *(const float4*)&wb[(size_t)(k + 0) * 128];
        float4 w1 = *(const float4*)&wb[(size_t)(k + 1) * 128];
        float4 w2 = *(const float4*)&wb[(size_t)(k + 2) * 128];
        float4 w3 = *(const float4*)&wb[(size_t)(k + 3) * 128];
#pragma unroll
        for (int r = 0; r < 8; ++r) {
            float4 a4 = *(const float4*)&ab[r * K + k];
            acc[r].x = fmaf(a4.x, w0.x, acc[r].x);
            acc[r].y = fmaf(a4.x, w0.y, acc[r].y);
            acc[r].z = fmaf(a4.x, w0.z, acc[r].z);
            acc[r].w = fmaf(a4.x, w0.w, acc[r].w);
            acc[r].x = fmaf(a4.y, w1.x, acc[r].x);
            acc[r].y = fmaf(a4.y, w1.y, acc[r].y);
            acc[r].z = fmaf(a4.y, w1.z, acc[r].z);
            acc[r].w = fmaf(a4.y, w1.w, acc[r].w);
            acc[r].x = fmaf(a4.z, w2.x, acc[r].x);
            acc[r].y = fmaf(a4.z, w2.y, acc[r].y);
            acc[r].z = fmaf(a4.z, w2.z, acc[r].z);
            acc[r].w = fmaf(a4.z, w2.w, acc[r].w);
            acc[r].x = fmaf(a4.w, w3.x, acc[r].x);
            acc[r].y = fmaf(a4.w, w3.y, acc[r].y);
            acc[r].z = fmaf(a4.w, w3.z, acc[r].z);
            acc[r].w = fmaf(a4.w, w3.w, acc[r].w);
        }
    }

    float4 b4 = *(const float4*)&bias[tx * 4];
#pragma unroll
    for (int r = 0; r < 8; ++r) {
        int gr = r0 + ty * 8 + r;
        if (gr < n) {
            uint2 st;
            st.x = pack2_bf16_rne(acc[r].x + b4.x, acc[r].y + b4.y);
            st.y = pack2_bf16_rne(acc[r].z + b4.z, acc[r].w + b4.w);
            *(uint2*)&C16[(size_t)gr * 128 + tx * 4] = st;
        }
    }
}

// ---------------- MFMA GEMM dual (swapped operands, packed bf16 stores) ----------------
__global__ __launch_bounds__(256) void gemm_mfma_dual(
    const unsigned short* __restrict__ A16,
    const unsigned short* __restrict__ B1t, const unsigned short* __restrict__ B2t,
    const float* __restrict__ bias1, const float* __restrict__ bias2,
    unsigned short* __restrict__ C1, unsigned short* __restrict__ C2, int n) {
    const int wave = threadIdx.x >> 6;
    const int lane = threadIdx.x & 63;
    const int r = lane & 15, g = lane >> 4;
    const int m0 = blockIdx.x * 64 + wave * 16;
    int ra = m0 + r; if (ra > n - 1) ra = n - 1;
    const bf16x8* Arow = (const bf16x8*)(A16 + (size_t)ra * 128);
    bf16x8 a0 = Arow[g];
    bf16x8 a1 = Arow[4 + g];
    bf16x8 a2 = Arow[8 + g];
    bf16x8 a3 = Arow[12 + g];
    const int row = m0 + r;
    const bool rok = row < n;
#pragma unroll
    for (int ct = 0; ct < 8; ++ct) {
        const int col = ct * 16 + g * 4;
        {
            const bf16x8* Brow = (const bf16x8*)(B1t + (size_t)(ct * 16 + r) * 128);
            f32x4 acc = {0.f, 0.f, 0.f, 0.f};
            acc = __builtin_amdgcn_mfma_f32_16x16x32_bf16(Brow[g], a0, acc, 0, 0, 0);
            acc = __builtin_amdgcn_mfma_f32_16x16x32_bf16(Brow[4 + g], a1, acc, 0, 0, 0);
            acc = __builtin_amdgcn_mfma_f32_16x16x32_bf16(Brow[8 + g], a2, acc, 0, 0, 0);
            acc = __builtin_amdgcn_mfma_f32_16x16x32_bf16(Brow[12 + g], a3, acc, 0, 0, 0);
            float4 b4 = *(const float4*)&bias1[col];
            if (rok) {
                uint2 st;
                st.x = pack2_bf16_rne(acc[0] + b4.x, acc[1] + b4.y);
                st.y = pack2_bf16_rne(acc[2] + b4.z, acc[3] + b4.w);
                *(uint2*)&C1[(size_t)row * 128 + col] = st;
            }
        }
        {
            const bf16x8* Brow = (const bf16x8*)(B2t + (size_t)(ct * 16 + r) * 128);
            f32x4 acc = {0.f, 0.f, 0.f, 0.f};
            acc = __builtin_amdgcn_mfma_f32_16x16x32_bf16(Brow[g], a0, acc, 0, 0, 0);
            acc = __builtin_amdgcn_mfma_f32_16x16x32_bf16(Brow[4 + g], a1, acc, 0, 0, 0);
            acc = __builtin_amdgcn_mfma_f32_16x16x32_bf16(Brow[8 + g], a2, acc, 0, 0, 0);
            acc = __builtin_amdgcn_mfma_f32_16x16x32_bf16(Brow[12 + g], a3, acc, 0, 0, 0);
            float4 b4 = *(const float4*)&bias2[col];
            if (rok) {
                uint2 st;
                st.x = pack2_bf16_rne(acc[0] + b4.x, acc[1] + b4.y);
                st.y = pack2_bf16_rne(acc[2] + b4.z, acc[3] + b4.w);
                *(uint2*)&C2[(size_t)row * 128 + col] = st;
            }
        }
    }
}

// ---------------- fused GATv2 aggregate + residuals + LayerNorm + ReLU ----------------
template <bool LAST>
__global__ __launch_bounds__(256) void gat_aggregate(
    unsigned short* __restrict__ h16,        // [n,128] bf16 residual in / out
    const unsigned short* __restrict__ hs16, // [n,128] bf16 (gathered)
    const unsigned short* __restrict__ hd16, // [n,128] bf16 (scores only)
    const int* __restrict__ cnt,             // [n] in-degree
    const int* __restrict__ slots,           // [n*CAP] src ids
    const float* __restrict__ attn,
    const float* __restrict__ ln_g, const float* __restrict__ ln_b,
    float* __restrict__ out_f32, int n) {
    int v = (blockIdx.x * blockDim.x + threadIdx.x) >> 6;
    int lane = threadIdx.x & 63;
    if (v >= n) return;
    const int lh = lane & 15;
    const int quarter = lane >> 4;
    const int f0 = lh * 8;
    const unsigned fb = (unsigned)lh << 4;

    const float L2E = 1.4426950408889634f;
    f32x2 av0, av1, av2, av3;
    {
        float4 aa = *(const float4*)&attn[f0];
        float4 ab = *(const float4*)&attn[f0 + 4];
        av0 = (f32x2){aa.x, aa.y} * L2E; av1 = (f32x2){aa.z, aa.w} * L2E;
        av2 = (f32x2){ab.x, ab.y} * L2E; av3 = (f32x2){ab.z, ab.w} * L2E;
    }
    const char* hsb = (const char*)hs16;
    f32x2 hd0, hd1, hd2, hd3;
    {
        uint4 wd = *(const uint4*)((const char*)hd16 + ((size_t)(unsigned)v << 8) + fb);
        hd0 = unpack_bf(wd.x); hd1 = unpack_bf(wd.y);
        hd2 = unpack_bf(wd.z); hd3 = unpack_bf(wd.w);
    }
    uint4 wv = *(const uint4*)(hsb + ((size_t)(unsigned)v << 8) + fb);
    f32x2 sv0 = unpack_bf(wv.x), sv1 = unpack_bf(wv.y);
    f32x2 sv2 = unpack_bf(wv.z), sv3 = unpack_bf(wv.w);
    float m;
    {
        f32x2 q0 = leaky2(sv0 + hd0), q1 = leaky2(sv1 + hd1);
        f32x2 q2 = leaky2(sv2 + hd2), q3 = leaky2(sv3 + hd3);
        f32x2 dt = q0 * av0; dt += q1 * av1; dt += q2 * av2; dt += q3 * av3;
        m = row_sum4(dt.x + dt.y);
    }
    const bool q0lane = (quarter == 0);
    float s = q0lane ? 1.f : 0.f;
    f32x2 acc0 = q0lane ? sv0 : (f32x2){0.f, 0.f};
    f32x2 acc1 = q0lane ? sv1 : (f32x2){0.f, 0.f};
    f32x2 acc2 = q0lane ? sv2 : (f32x2){0.f, 0.f};
    f32x2 acc3 = q0lane ? sv3 : (f32x2){0.f, 0.f};

    int deg = cnt[v]; if (deg > CAP) deg = CAP;
    const int* srow = slots + (size_t)v * CAP;
    int end4 = deg & ~3;

    auto process = [&](uint4 w) {
        f32x2 g0 = unpack_bf(w.x), g1 = unpack_bf(w.y);
        f32x2 g2 = unpack_bf(w.z), g3 = unpack_bf(w.w);
        f32x2 p0 = leaky2(g0 + hd0), p1 = leaky2(g1 + hd1);
        f32x2 p2 = leaky2(g2 + hd2), p3 = leaky2(g3 + hd3);
        f32x2 dt = p0 * av0; dt += p1 * av1; dt += p2 * av2; dt += p3 * av3;
        float sc = row_sum4(dt.x + dt.y);
        float d0 = sc - m;
        if (__builtin_expect(__any(d0 > 8.f), 0)) {
            float dmx = fmaxf(d0, __shfl_xor(d0, 16));
            dmx = fmaxf(dmx, __shfl_xor(dmx, 32));
            float mn = m + fmaxf(dmx, 0.f);
            float rr = exp2f(m - mn);
            s *= rr; acc0 *= rr; acc1 *= rr; acc2 *= rr; acc3 *= rr;
            m = mn; d0 = sc - m;
        }
        float e = exp2f(d0);
        s += e;
        acc0 += g0 * e; acc1 += g1 * e; acc2 += g2 * e; acc3 += g3 * e;
    };

    if (end4 > 0) {
        uint4 w = *(const uint4*)(hsb + ((size_t)(unsigned)srow[quarter] << 8) + fb);
        int un = (4 < end4) ? srow[4 + quarter] : 0;
        for (int i = 4; i < end4; i += 4) {
            uint4 wn = *(const uint4*)(hsb + ((size_t)(unsigned)un << 8) + fb);
            if (i + 4 < end4) un = srow[i + 4 + quarter];
            process(w);
            w = wn;
        }
        process(w);
    }
    if (end4 < deg) {
        int idx = end4 + quarter;
        bool act = idx < deg;
        int u = srow[act ? idx : end4];
        uint4 w = *(const uint4*)(hsb + ((size_t)(unsigned)u << 8) + fb);
        f32x2 g0 = unpack_bf(w.x), g1 = unpack_bf(w.y);
        f32x2 g2 = unpack_bf(w.z), g3 = unpack_bf(w.w);
        f32x2 p0 = leaky2(g0 + hd0), p1 = leaky2(g1 + hd1);
        f32x2 p2 = leaky2(g2 + hd2), p3 = leaky2(g3 + hd3);
        f32x2 dt = p0 * av0; dt += p1 * av1; dt += p2 * av2; dt += p3 * av3;
        float sc = row_sum4(dt.x + dt.y);
        float d0 = sc - m;
        float d0m = act ? d0 : -1e30f;
        if (__builtin_expect(__any(d0m > 8.f), 0)) {
            float dmx = fmaxf(d0m, __shfl_xor(d0m, 16));
            dmx = fmaxf(dmx, __shfl_xor(dmx, 32));
            float mn = m + fmaxf(dmx, 0.f);
            float rr = exp2f(m - mn);
            s *= rr; acc0 *= rr; acc1 *= rr; acc2 *= rr; acc3 *= rr;
            m = mn; d0 = sc - m;
        }
        float e = act ? exp2f(d0) : 0.f;
        s += e;
        acc0 += g0 * e; acc1 += g1 * e; acc2 += g2 * e; acc3 += g3 * e;
    }
#pragma unroll
    for (int d = 16; d <= 32; d <<= 1) {
        s += __shfl_xor(s, d);
        acc0.x += __shfl_xor(acc0.x, d); acc0.y += __shfl_xor(acc0.y, d);
        acc1.x += __shfl_xor(acc1.x, d); acc1.y += __shfl_xor(acc1.y, d);
        acc2.x += __shfl_xor(acc2.x, d); acc2.y += __shfl_xor(acc2.y, d);
        acc3.x += __shfl_xor(acc3.x, d); acc3.y += __shfl_xor(acc3.y, d);
    }
    float inv = 1.0f / (s + 1e-9f);

    f32x2 hv0, hv1, hv2, hv3;
    {
        uint4 wh = *(const uint4*)((const char*)h16 + ((size_t)(unsigned)v << 8) + fb);
        hv0 = unpack_bf(wh.x); hv1 = unpack_bf(wh.y);
        hv2 = unpack_bf(wh.z); hv3 = unpack_bf(wh.w);
    }
    f32x2 x0 = acc0 * inv + hv0 * 2.f;
    f32x2 x1 = acc1 * inv + hv1 * 2.f;
    f32x2 x2 = acc2 * inv + hv2 * 2.f;
    f32x2 x3 = acc3 * inv + hv3 * 2.f;

    f32x2 sum2 = (x0 + x1) + (x2 + x3);
    f32x2 sq2 = x0 * x0 + x1 * x1 + x2 * x2 + x3 * x3;
    float sum = sum2.x + sum2.y, sq = sq2.x + sq2.y;
#pragma unroll
    for (int d = 1; d < 64; d <<= 1) { sum += __shfl_xor(sum, d); sq += __shfl_xor(sq, d); }
    float mu = sum * (1.f / 512.f);
    float var = sq * (1.f / 512.f) - mu * mu;
    float rstd = rsqrtf(var + 1e-5f);
    f32x2 g0v, g1v, g2v, g3v, b0v, b1v, b2v, b3v;
    {
        float4 ga = *(const float4*)&ln_g[f0];
        float4 gb = *(const float4*)&ln_g[f0 + 4];
        float4 ba = *(const float4*)&ln_b[f0];
        float4 bb = *(const float4*)&ln_b[f0 + 4];
        g0v = (f32x2){ga.x, ga.y}; g1v = (f32x2){ga.z, ga.w};
        g2v = (f32x2){gb.x, gb.y}; g3v = (f32x2){gb.z, gb.w};
        b0v = (f32x2){ba.x, ba.y}; b1v = (f32x2){ba.z, ba.w};
        b2v = (f32x2){bb.x, bb.y}; b3v = (f32x2){bb.z, bb.w};
    }
    f32x2 zero = {0.f, 0.f};
    f32x2 y0 = __builtin_elementwise_max((x0 - mu) * rstd * g0v + b0v, zero);
    f32x2 y1 = __builtin_elementwise_max((x1 - mu) * rstd * g1v + b1v, zero);
    f32x2 y2 = __builtin_elementwise_max((x2 - mu) * rstd * g2v + b2v, zero);
    f32x2 y3 = __builtin_elementwise_max((x3 - mu) * rstd * g3v + b3v, zero);
    if (quarter == 0) {
        uint4 st;
        st.x = pack2_bf16_rne(y0.x, y0.y);
        st.y = pack2_bf16_rne(y1.x, y1.y);
        st.z = pack2_bf16_rne(y2.x, y2.y);
        st.w = pack2_bf16_rne(y3.x, y3.y);
        *(uint4*)((char*)h16 + ((size_t)v << 8) + fb) = st;
        if (LAST) {
            float* orow = &out_f32[(size_t)v * 128 + f0];
            *(float4*)orow = make_float4(y0.x, y0.y, y1.x, y1.y);
            *(float4*)(orow + 4) = make_float4(y2.x, y2.y, y3.x, y3.y);
        }
    }
}

// ---------------- fused node-MLP + heads (fused dot in ct-loop) + graph-mean ----------------
// blocks [0,nMLP): z1 -> LDS bf16; per ct: z tile (4 floats) -> immediately
// FMA into 6 head accumulators (no zc array -> no spill); reduce shfl 16,32.
// blocks [nMLP, nMLP+MB): mean-partial over out_nemb.
__global__ __launch_bounds__(256) void mlp_heads_mean(
    const unsigned short* __restrict__ h16,
    const unsigned short* __restrict__ W1t, const unsigned short* __restrict__ W2t,
    const float* __restrict__ b1, const float* __restrict__ b2,
    const float* __restrict__ Wa, const float* __restrict__ ba,
    const float* __restrict__ Wg, const float* __restrict__ bg,
    const float* __restrict__ Wal, const float* __restrict__ bal,
    const float* __restrict__ Wn, const float* __restrict__ bn,
    const float* __restrict__ Wt, const float* __restrict__ bt,
    float* __restrict__ logits, float* __restrict__ spawn,
    const float* __restrict__ nemb, float* __restrict__ gacc,
    int n, int nMLP, int MB) {
    if ((int)blockIdx.x >= nMLP) {
        const float4* srcp = (const float4*)nemb;
        size_t n4 = (size_t)n * 32;
        int tid = threadIdx.x;
        size_t i = ((int)blockIdx.x - nMLP) * (size_t)256 + tid;
        size_t stride = (size_t)MB * 256;
        float ax = 0.f, ay = 0.f, az = 0.f, aw = 0.f;
        for (; i < n4; i += stride) {
            float4 v = srcp[i];
            ax += v.x; ay += v.y; az += v.z; aw += v.w;
        }
        __shared__ float4 sb[256];
        sb[tid] = make_float4(ax, ay, az, aw);
        __syncthreads();
        for (int off2 = 128; off2 >= 32; off2 >>= 1) {
            if (tid < off2) {
                float4 o = sb[tid + off2];
                sb[tid].x += o.x; sb[tid].y += o.y; sb[tid].z += o.z; sb[tid].w += o.w;
            }
            __syncthreads();
        }
        if (tid < 32) {
            float4 a = sb[tid];
            atomicAdd(&gacc[tid * 4 + 0], a.x);
            atomicAdd(&gacc[tid * 4 + 1], a.y);
            atomicAdd(&gacc[tid * 4 + 2], a.z);
            atomicAdd(&gacc[tid * 4 + 3], a.w);
        }
        return;
    }
    __shared__ __align__(16) unsigned short z1l[64 * 136]; // 17408B

    const int wave = threadIdx.x >> 6;
    const int lane = threadIdx.x & 63;
    const int r = lane & 15, g = lane >> 4;
    const int m0 = blockIdx.x * 64 + wave * 16;
    int ra = m0 + r; if (ra > n - 1) ra = n - 1;
    const int lrow = wave * 16 + r;

    // stage 1: z1 -> LDS (bf16)
    {
        const bf16x8* Arow = (const bf16x8*)(h16 + (size_t)ra * 128);
        bf16x8 a0 = Arow[g];
        bf16x8 a1 = Arow[4 + g];
        bf16x8 a2 = Arow[8 + g];
        bf16x8 a3 = Arow[12 + g];
#pragma unroll
        for (int ct = 0; ct < 8; ++ct) {
            const bf16x8* Brow = (const bf16x8*)(W1t + (size_t)(ct * 16 + r) * 128);
            f32x4 acc = {0.f, 0.f, 0.f, 0.f};
            acc = __builtin_amdgcn_mfma_f32_16x16x32_bf16(Brow[g], a0, acc, 0, 0, 0);
            acc = __builtin_amdgcn_mfma_f32_16x16x32_bf16(Brow[4 + g], a1, acc, 0, 0, 0);
            acc = __builtin_amdgcn_mfma_f32_16x16x32_bf16(Brow[8 + g], a2, acc, 0, 0, 0);
            acc = __builtin_amdgcn_mfma_f32_16x16x32_bf16(Brow[12 + g], a3, acc, 0, 0, 0);
            const int col = ct * 16 + g * 4;
            float4 bb = *(const float4*)&b1[col];
            uint2 st;
            st.x = pack2_bf16_rne(fmaxf(acc[0] + bb.x, 0.f), fmaxf(acc[1] + bb.y, 0.f));
            st.y = pack2_bf16_rne(fmaxf(acc[2] + bb.z, 0.f), fmaxf(acc[3] + bb.w, 0.f));
            *(uint2*)&z1l[lrow * 136 + col] = st;
        }
    }
    __syncthreads();
    // stage 2+3: per ct compute z tile, immediately accumulate head dots
    float p0 = 0.f, p1 = 0.f, p2 = 0.f, p3 = 0.f, p4 = 0.f, p5 = 0.f;
    {
        const unsigned short* zrow = &z1l[lrow * 136];
        bf16x8 a0 = *(const bf16x8*)&zrow[g * 8];
        bf16x8 a1 = *(const bf16x8*)&zrow[32 + g * 8];
        bf16x8 a2 = *(const bf16x8*)&zrow[64 + g * 8];
        bf16x8 a3 = *(const bf16x8*)&zrow[96 + g * 8];
#pragma unroll
        for (int ct = 0; ct < 8; ++ct) {
            const bf16x8* Brow = (const bf16x8*)(W2t + (size_t)(ct * 16 + r) * 128);
            f32x4 acc = {0.f, 0.f, 0.f, 0.f};
            acc = __builtin_amdgcn_mfma_f32_16x16x32_bf16(Brow[g], a0, acc, 0, 0, 0);
            acc = __builtin_amdgcn_mfma_f32_16x16x32_bf16(Brow[4 + g], a1, acc, 0, 0, 0);
            acc = __builtin_amdgcn_mfma_f32_16x16x32_bf16(Brow[8 + g], a2, acc, 0, 0, 0);
            acc = __builtin_amdgcn_mfma_f32_16x16x32_bf16(Brow[12 + g], a3, acc, 0, 0, 0);
            const int f = ct * 16 + g * 4;
            float4 bb = *(const float4*)&b2[f];
            float z0 = fmaxf(acc[0] + bb.x, 0.f);
            float z1v = fmaxf(acc[1] + bb.y, 0.f);
            float z2 = fmaxf(acc[2] + bb.z, 0.f);
            float z3 = fmaxf(acc[3] + bb.w, 0.f);
            float4 waA = *(const float4*)&Wa[f * 2];       // rows f,f+1 (2 cols each)
            float4 waB = *(const float4*)&Wa[f * 2 + 4];   // rows f+2,f+3
            float4 wg4 = *(const float4*)&Wg[f];
            float4 wl4 = *(const float4*)&Wal[f];
            float4 wn4 = *(const float4*)&Wn[f];
            float4 wt4 = *(const float4*)&Wt[f];
            p0 = fmaf(z0, waA.x, fmaf(z1v, waA.z, fmaf(z2, waB.x, fmaf(z3, waB.z, p0))));
            p1 = fmaf(z0, waA.y, fmaf(z1v, waA.w, fmaf(z2, waB.y, fmaf(z3, waB.w, p1))));
            p2 = fmaf(z0, wg4.x, fmaf(z1v, wg4.y, fmaf(z2, wg4.z, fmaf(z3, wg4.w, p2))));
            p3 = fmaf(z0, wl4.x, fmaf(z1v, wl4.y, fmaf(z2, wl4.z, fmaf(z3, wl4.w, p3))));
            p4 = fmaf(z0, wn4.x, fmaf(z1v, wn4.y, fmaf(z2, wn4.z, fmaf(z3, wn4.w, p4))));
            p5 = fmaf(z0, wt4.x, fmaf(z1v, wt4.y, fmaf(z2, wt4.z, fmaf(z3, wt4.w, p5))));
        }
    }
#pragma unroll
    for (int d = 16; d <= 32; d <<= 1) {
        p0 += __shfl_xor(p0, d); p1 += __shfl_xor(p1, d); p2 += __shfl_xor(p2, d);
        p3 += __shfl_xor(p3, d); p4 += __shfl_xor(p4, d); p5 += __shfl_xor(p5, d);
    }
    int v = m0 + r;
    if (g == 0 && v < n) {
        logits[(size_t)v * 2 + 0] = p0 + ba[0];
        logits[(size_t)v * 2 + 1] = p1 + ba[1];
        float gamma = 5.f / (1.f + __expf(-(p2 + bg[0])));
        float alpha = 2.f / (1.f + __expf(-(p3 + bal[0])));
        float noise = 1.f / (1.f + __expf(-(p4 + bn[0])));
        float theta = tanhf(p5 + bt[0]) * 3.14159265358979323846f;
        spawn[(size_t)v * 4 + 0] = gamma;
        spawn[(size_t)v * 4 + 1] = alpha;
        spawn[(size_t)v * 4 + 2] = noise;
        spawn[(size_t)v * 4 + 3] = theta;
    }
}

__global__ void graph_mean_final(const float* __restrict__ gacc, float* __restrict__ out, int n) {
    int c = threadIdx.x; // 128
    out[c] = gacc[c] / (float)n;
}

extern "C" void kernel_launch(void* const* d_in, const int* in_sizes, int n_in,
                              void* d_out, int out_size, void* d_ws, size_t ws_size,
                              hipStream_t stream) {
    const float* node_feats = (const float*)d_in[0];
    const int*   src  = (const int*)d_in[1];
    const int*   dst  = (const int*)d_in[2];
    const float* W_in = (const float*)d_in[3];
    const float* b_in = (const float*)d_in[4];
    const float* W_src = (const float*)d_in[5];
    const float* b_src = (const float*)d_in[6];
    const float* W_dst = (const float*)d_in[7];
    const float* b_dst = (const float*)d_in[8];
    const float* attn  = (const float*)d_in[9];
    const float* ln_g  = (const float*)d_in[10];
    const float* ln_b  = (const float*)d_in[11];
    const float* W1 = (const float*)d_in[12]; const float* b1 = (const float*)d_in[13];
    const float* W2 = (const float*)d_in[14]; const float* b2 = (const float*)d_in[15];
    const float* Wa = (const float*)d_in[16]; const float* ba = (const float*)d_in[17];
    const float* Wg = (const float*)d_in[18]; const float* bg = (const float*)d_in[19];
    const float* Wal = (const float*)d_in[20]; const float* bal = (const float*)d_in[21];
    const float* Wn = (const float*)d_in[22]; const float* bn = (const float*)d_in[23];
    const float* Wt = (const float*)d_in[24]; const float* bt = (const float*)d_in[25];

    const int n = in_sizes[0] / 32;  // 50000
    const int E = in_sizes[1];       // 1600000
    const int qg = (n + 7) / 8;      // 6250 < 8192 (13-bit local dst)
    const int BCAP = 240 * 1024;
    const int ntiles = (E + TILE2 - 1) / TILE2;

    char* ws = (char*)d_ws;
    size_t off = 0;
    auto alloc = [&](size_t bytes) -> void* {
        void* p = ws + off;
        off = (off + bytes + 255) & ~(size_t)255;
        return p;
    };
    unsigned short* h16  = (unsigned short*)alloc((size_t)n * 128 * 2);
    unsigned short* hs16 = (unsigned short*)alloc((size_t)n * 128 * 2);
    unsigned short* hd16 = (unsigned short*)alloc((size_t)n * 128 * 2);
    unsigned short* Wt16 = (unsigned short*)alloc((size_t)8 * 16384 * 2);
    int* cnt   = (int*)alloc((size_t)n * 4);
    int* slots = (int*)alloc((size_t)n * CAP * 4);
    unsigned* buckets = (unsigned*)alloc((size_t)8 * BCAP * 4);
    int* tails = (int*)alloc(8 * 4);
    float* gacc = (float*)alloc(128 * 4);

    float* out = (float*)d_out;
    float* out_gemb   = out;
    float* out_nemb   = out + 128;
    float* out_logits = out + 128 + (size_t)n * 128;
    float* out_spawn  = out_logits + (size_t)n * 2;

    hipMemsetAsync(cnt, 0, (size_t)n * 4, stream);
    hipMemsetAsync(tails, 0, 8 * 4, stream);
    hipMemsetAsync(gacc, 0, 128 * 4, stream);

    partition_and_prep<<<ntiles + 8, 256, 0, stream>>>(
        src, dst, tails, buckets, BCAP, E, qg, ntiles, W_src, W_dst, W1, W2, Wt16);
    fill_slots<<<2048, 256, 0, stream>>>(buckets, tails, cnt, slots, BCAP, qg);

    int gemm_grid = (n + GR - 1) / GR;
    int mfma_grid = (n + 63) / 64;

    gemm_in<<<gemm_grid, 256, 0, stream>>>(node_feats, W_in, b_in, h16, n);

    for (int l = 0; l < 3; ++l) {
        gemm_mfma_dual<<<mfma_grid, 256, 0, stream>>>(
            h16, Wt16 + (size_t)l * 16384, Wt16 + (size_t)(3 + l) * 16384,
            b_src + l * 128, b_dst + l * 128, hs16, hd16, n);
        if (l == 2)
            gat_aggregate<true><<<(n + 3) / 4, 256, 0, stream>>>(
                h16, hs16, hd16, cnt, slots, attn + l * 128, ln_g + l * 128,
                ln_b + l * 128, out_nemb, n);
        else
            gat_aggregate<false><<<(n + 3) / 4, 256, 0, stream>>>(
                h16, hs16, hd16, cnt, slots, attn + l * 128, ln_g + l * 128,
                ln_b + l * 128, nullptr, n);
    }

    const int MB = 512;
    mlp_heads_mean<<<mfma_grid + MB, 256, 0, stream>>>(
        h16, Wt16 + (size_t)6 * 16384, Wt16 + (size_t)7 * 16384, b1, b2,
        Wa, ba, Wg, bg, Wal, bal, Wn, bn, Wt, bt,
        out_logits, out_spawn, out_nemb, gacc, n, mfma_grid, MB);
    graph_mean_final<<<1, 128, 0, stream>>>(gacc, out_gemb, n);
}